// Round 6
// baseline (314.173 us; speedup 1.0000x reference)
//
#include <hip/hip_runtime.h>
#include <cstdint>
#include <cstddef>

#define D_MODEL 1024
#define N_EXPERTS 8
#define FFN_H 2048
#define N_TOK 4096
#define CAP 2048

typedef float f32x4 __attribute__((ext_vector_type(4)));
typedef __bf16 bf16x8 __attribute__((ext_vector_type(8)));

// ---- workspace layout (bytes) ----
static constexpr size_t XB_OFF   = 0;                                                  // [N][D] bf16
static constexpr size_t W1B_OFF  = XB_OFF  + (size_t)N_TOK * D_MODEL * 2;
static constexpr size_t W2B_OFF  = W1B_OFF + (size_t)N_EXPERTS * FFN_H * D_MODEL * 2;
static constexpr size_t HBUF_OFF = W2B_OFF + (size_t)N_EXPERTS * D_MODEL * FFN_H * 2;  // [E][CAP][H] bf16
static constexpr size_t YBUF_OFF = HBUF_OFF + (size_t)N_EXPERTS * CAP * FFN_H * 2;     // [E][CAP][D] bf16
static constexpr size_t CNT_OFF  = YBUF_OFF + (size_t)N_EXPERTS * CAP * D_MODEL * 2;   // [8] int
static constexpr size_t PSUM_OFF = CNT_OFF + 32;                                       // [8] float
static constexpr size_t TOK_OFF  = PSUM_OFF + 32;                                      // [E][CAP] int
static constexpr size_t TIX_OFF  = TOK_OFF + (size_t)N_EXPERTS * CAP * 4;              // [N] int2
static constexpr size_t TIW_OFF  = TIX_OFF + (size_t)N_TOK * 8;                        // [N] float2

// async global->LDS, 16 B per lane; LDS dest = wave-uniform base + lane*16
__device__ __forceinline__ void async_ld16(const void* g, void* l) {
    __builtin_amdgcn_global_load_lds(
        (const __attribute__((address_space(1))) unsigned int*)g,
        (__attribute__((address_space(3))) unsigned int*)l, 16, 0, 0);
}

#define VMWAIT(n) asm volatile("s_waitcnt vmcnt(" #n ")" ::: "memory")
#define SBAR()    asm volatile("s_barrier" ::: "memory")

__device__ __forceinline__ void cvt_block256(const float* __restrict__ src,
                                             __bf16* __restrict__ dst,
                                             int c, int tid) {
    size_t i = (size_t)c * 2048 + (size_t)tid * 8;
    float4 a = *reinterpret_cast<const float4*>(src + i);
    float4 d = *reinterpret_cast<const float4*>(src + i + 4);
    bf16x8 r;
    r[0] = (__bf16)a.x; r[1] = (__bf16)a.y; r[2] = (__bf16)a.z; r[3] = (__bf16)a.w;
    r[4] = (__bf16)d.x; r[5] = (__bf16)d.y; r[6] = (__bf16)d.z; r[7] = (__bf16)d.w;
    *reinterpret_cast<bf16x8*>(dst + i) = r;
}

// ---------------- prep: blocks 0..63 = router; 64..2111 = x cvt; 2112.. = w1 cvt ----------------
__global__ __launch_bounds__(256) void prep_kernel(const float* __restrict__ x,
                                                   const float* __restrict__ rw,
                                                   const float* __restrict__ w1,
                                                   __bf16* __restrict__ xb,
                                                   __bf16* __restrict__ w1b,
                                                   int* __restrict__ counts,
                                                   float* __restrict__ psum,
                                                   int* __restrict__ tok_list,
                                                   int2* __restrict__ tinfo_idx,
                                                   float2* __restrict__ tinfo_w) {
    __shared__ float rws[N_EXPERTS * D_MODEL];   // 32 KB (router blocks only)
    __shared__ int s_e0[64], s_e1[64], s_r0[64], s_r1[64];
    __shared__ float s_w0[64], s_w1[64];
    __shared__ int hist[8], base[8];
    __shared__ float pacc[8];

    int tid = threadIdx.x;
    int b = blockIdx.x;
    if (b >= 64) {
        int c = b - 64;
        if (c < 2048) cvt_block256(x, xb, c, tid);
        else          cvt_block256(w1, w1b, c - 2048, tid);
        return;
    }

    // ---- router path: 64 tokens per block ----
    for (int i = tid * 4; i < N_EXPERTS * D_MODEL; i += 256 * 4)
        *reinterpret_cast<float4*>(&rws[i]) = *reinterpret_cast<const float4*>(&rw[i]);
    if (tid < 8) { hist[tid] = 0; pacc[tid] = 0.f; }
    __syncthreads();

    int wave = tid >> 6, lane = tid & 63;
    float psacc[8] = {};
    for (int it = 0; it < 16; ++it) {
        int li = wave * 16 + it;
        int t = b * 64 + li;
        const float* xr = x + (size_t)t * D_MODEL;
        float acc[8] = {};
#pragma unroll
        for (int i = 0; i < D_MODEL / 64; ++i) {
            float xv = xr[lane + 64 * i];
#pragma unroll
            for (int e = 0; e < 8; ++e) acc[e] += xv * rws[e * D_MODEL + lane + 64 * i];
        }
        float logit[8];
#pragma unroll
        for (int e = 0; e < 8; ++e) {
            float v = acc[e];
            for (int off = 32; off; off >>= 1) v += __shfl_xor(v, off);
            logit[e] = v;
        }
        float mx = logit[0];
#pragma unroll
        for (int e = 1; e < 8; ++e) mx = fmaxf(mx, logit[e]);
        float p[8], s = 0.f;
#pragma unroll
        for (int e = 0; e < 8; ++e) { p[e] = expf(logit[e] - mx); s += p[e]; }
        float inv = 1.f / s;
#pragma unroll
        for (int e = 0; e < 8; ++e) { p[e] *= inv; psacc[e] += p[e]; }
        int e0 = 0; float p0 = p[0];
#pragma unroll
        for (int e = 1; e < 8; ++e) if (p[e] > p0) { p0 = p[e]; e0 = e; }
        int e1 = -1; float p1 = -1.f;
#pragma unroll
        for (int e = 0; e < 8; ++e) if (e != e0 && p[e] > p1) { p1 = p[e]; e1 = e; }
        float invw = 1.f / (p0 + p1);
        if (lane == 0) {
            s_e0[li] = e0; s_e1[li] = e1;
            s_w0[li] = p0 * invw; s_w1[li] = p1 * invw;
        }
    }
    if (lane == 0)
#pragma unroll
        for (int e = 0; e < 8; ++e) atomicAdd(&pacc[e], psacc[e]);
    __syncthreads();

    if (tid < 64) {
        s_r0[tid] = atomicAdd(&hist[s_e0[tid]], 1);
        s_r1[tid] = atomicAdd(&hist[s_e1[tid]], 1);
    }
    __syncthreads();
    if (tid < 8) {
        base[tid] = atomicAdd(&counts[tid], hist[tid]);   // device-scope, 512 total
        atomicAdd(&psum[tid], pacc[tid]);
    }
    __syncthreads();
    if (tid < 64) {
        int t = b * 64 + tid;
        int e0 = s_e0[tid], e1 = s_e1[tid];
        int q0 = min(base[e0] + s_r0[tid], CAP - 1);
        int q1 = min(base[e1] + s_r1[tid], CAP - 1);
        tok_list[e0 * CAP + q0] = t;
        tok_list[e1 * CAP + q1] = t;
        tinfo_idx[t] = make_int2(e0 * CAP + q0, e1 * CAP + q1);
        tinfo_w[t] = make_float2(s_w0[tid], s_w1[tid]);
    }
}

// ---------------- grouped GEMM, 8-phase-style schedule (m201/m248 port) ----------------
// BM=256, BN=128, BK=64. 512 threads = 8 waves (4m x 2n), per-wave out 64x64.
// LDS ring: 3 slots x (A 32768 + B 16384) = 147456 B -> 1 block/CU.
// Per K-tile: 2 phases, each {issue 3 gload_lds (tile t+2) ; ds_read subtile ;
//   s_barrier ; lgkmcnt(0) ; setprio(1) ; 16 MFMA ; setprio(0) ; [vmcnt] ; s_barrier}.
// vmcnt ledger (per thread, 6 loads/tile): prologue stages t0,t1 (12), VMWAIT(6)+SBAR
// -> t0 landed. Steady: entering tile t, 6 of t+1 in flight; phases issue 6 of t+2;
// end-of-tile VMWAIT(6) drains t+1's -> never 0 until tail (VMWAIT(0) at t==NTILE-2).
// Ring safety: slot (t+2)%3 == slot (t-1)%3; tile t-1's ds_reads completed (lgkmcnt 0)
// before its final barrier, which all waves passed before tile t issues staging.
// Swizzle (both sides, same involution): 16B col-block cb stored/read at cb ^ (row&7);
// a wave b128 frag-read then spreads exactly 128 B per bank-quad = the 8-cycle floor.
// CVT instantiation (pass1): w2 fp32->bf16 blocks interleaved 4:1 (bid%5!=0).
template <int KDIM, bool PASS2, bool CVT>
__global__ __launch_bounds__(512, 1) void ffn_kernel(const __bf16* __restrict__ A_base,
                                                     const __bf16* __restrict__ B_base,
                                                     const float* __restrict__ bias,
                                                     const int* __restrict__ counts,
                                                     const int* __restrict__ tok_list,
                                                     __bf16* __restrict__ Out_base,
                                                     const float* __restrict__ cvt_src,
                                                     __bf16* __restrict__ cvt_dst) {
    constexpr int BROWS = PASS2 ? D_MODEL : FFN_H;
    constexpr int NT = BROWS / 128;
    constexpr int NTILE = KDIM / 64;
    int bid = blockIdx.x;
    int tid = threadIdx.x;

    int gid;
    if (CVT) {
        int m5 = bid % 5;
        if (m5) {   // converter block: 512 threads x 8 floats = 4096 floats
            int c = (bid / 5) * 4 + m5 - 1;
            size_t i = (size_t)c * 4096 + (size_t)tid * 8;
            float4 a = *reinterpret_cast<const float4*>(cvt_src + i);
            float4 d = *reinterpret_cast<const float4*>(cvt_src + i + 4);
            bf16x8 rr_;
            rr_[0] = (__bf16)a.x; rr_[1] = (__bf16)a.y; rr_[2] = (__bf16)a.z; rr_[3] = (__bf16)a.w;
            rr_[4] = (__bf16)d.x; rr_[5] = (__bf16)d.y; rr_[6] = (__bf16)d.z; rr_[7] = (__bf16)d.w;
            *reinterpret_cast<bf16x8*>(cvt_dst + i) = rr_;
            return;
        }
        gid = bid / 5;
    } else {
        gid = bid;
    }

    int e = gid & 7;                 // expert fastest -> XCD-pinned weights (5 coprime 8)
    int r = gid >> 3;
    int n0 = (r % NT) * 128;
    int m0 = (r / NT) * 256;
    int cnt = min(counts[e], CAP);
    if (m0 >= cnt) return;

    __shared__ char smem[147456];    // 3 x (A 32K @ +0, B 16K @ +32768)

    int w = tid >> 6, lane = tid & 63;
    int sub = (tid >> 3) & 7;                 // lane>>3 within wave
    int cbs = ((tid & 7) ^ sub) * 8;          // pre-swizzled source col (elements)

    // ---- staging sources: per thread, A loads l=0..3 (rows 64l+8w+sub), B loads l=0..1 ----
    const __bf16* a_src[4];
    const __bf16* b_src[2];
    if (!PASS2) {
        int* s_tok = (int*)smem;
        if (tid < 256) s_tok[tid] = tok_list[e * CAP + min(m0 + tid, cnt - 1)];
        __syncthreads();
#pragma unroll
        for (int l = 0; l < 4; ++l)
            a_src[l] = A_base + (size_t)s_tok[64 * l + 8 * w + sub] * KDIM + cbs;
        __syncthreads();   // s_tok consumed before staging overwrites slot 0
    } else {
#pragma unroll
        for (int l = 0; l < 4; ++l)
            a_src[l] = A_base + ((size_t)e * CAP + min(m0 + 64 * l + 8 * w + sub, cnt - 1)) * KDIM + cbs;
    }
#pragma unroll
    for (int l = 0; l < 2; ++l)
        b_src[l] = B_base + ((size_t)e * BROWS + n0 + 64 * l + 8 * w + sub) * KDIM + cbs;

    int wm = w >> 1, wn = w & 1;              // 4m x 2n wave grid
    int lm = lane & 15, q = lane >> 4;
    int sw0 = (q ^ (lm & 7)) * 16;            // read-side swizzle, k-slice 0
    int sw1 = ((4 + q) ^ (lm & 7)) * 16;      // k-slice 1
    int a_rb = (wm * 64 + lm) * 128;          // A frag row base (bytes)
    int b_rb = 32768 + (wn * 64 + lm) * 128;  // B frag row base (bytes)

    auto stage_ph0 = [&](int t) {
        char* sb_ = smem + (t % 3) * 49152;
        async_ld16(a_src[0] + t * 64, sb_ + (0 * 8 + w) * 1024);
        async_ld16(a_src[1] + t * 64, sb_ + (1 * 8 + w) * 1024);
        async_ld16(b_src[0] + t * 64, sb_ + 32768 + (0 * 8 + w) * 1024);
    };
    auto stage_ph1 = [&](int t) {
        char* sb_ = smem + (t % 3) * 49152;
        async_ld16(a_src[2] + t * 64, sb_ + (2 * 8 + w) * 1024);
        async_ld16(a_src[3] + t * 64, sb_ + (3 * 8 + w) * 1024);
        async_ld16(b_src[1] + t * 64, sb_ + 32768 + (1 * 8 + w) * 1024);
    };

    f32x4 acc[4][4] = {};
    bf16x8 bfr0, bfr1, bfr2, bfr3, bfs0, bfs1, bfs2, bfs3;   // B frags, persist ph0->ph1

    // prologue: tiles 0,1 in flight (12 loads/thread)
    stage_ph0(0); stage_ph1(0); stage_ph0(1); stage_ph1(1);
    VMWAIT(6);   // tile 0 landed (all waves), 6 (tile 1) in flight
    SBAR();

    for (int t = 0; t < NTILE; ++t) {
        const char* sb_ = smem + (t % 3) * 49152;
        // ---------- phase 0: B frags + A m-half 0 ----------
        if (t + 2 < NTILE) stage_ph0(t + 2);
        bf16x8 a00, a01, a10, a11;
        bfr0 = *reinterpret_cast<const bf16x8*>(sb_ + b_rb + 0 * 2048 + sw0);
        bfs0 = *reinterpret_cast<const bf16x8*>(sb_ + b_rb + 0 * 2048 + sw1);
        bfr1 = *reinterpret_cast<const bf16x8*>(sb_ + b_rb + 1 * 2048 + sw0);
        bfs1 = *reinterpret_cast<const bf16x8*>(sb_ + b_rb + 1 * 2048 + sw1);
        bfr2 = *reinterpret_cast<const bf16x8*>(sb_ + b_rb + 2 * 2048 + sw0);
        bfs2 = *reinterpret_cast<const bf16x8*>(sb_ + b_rb + 2 * 2048 + sw1);
        bfr3 = *reinterpret_cast<const bf16x8*>(sb_ + b_rb + 3 * 2048 + sw0);
        bfs3 = *reinterpret_cast<const bf16x8*>(sb_ + b_rb + 3 * 2048 + sw1);
        a00 = *reinterpret_cast<const bf16x8*>(sb_ + a_rb + 0 * 2048 + sw0);
        a01 = *reinterpret_cast<const bf16x8*>(sb_ + a_rb + 0 * 2048 + sw1);
        a10 = *reinterpret_cast<const bf16x8*>(sb_ + a_rb + 1 * 2048 + sw0);
        a11 = *reinterpret_cast<const bf16x8*>(sb_ + a_rb + 1 * 2048 + sw1);
        SBAR();
        asm volatile("s_waitcnt lgkmcnt(0)" ::: "memory");
        __builtin_amdgcn_sched_barrier(0);
        __builtin_amdgcn_s_setprio(1);
        acc[0][0] = __builtin_amdgcn_mfma_f32_16x16x32_bf16(a00, bfr0, acc[0][0], 0, 0, 0);
        acc[0][1] = __builtin_amdgcn_mfma_f32_16x16x32_bf16(a00, bfr1, acc[0][1], 0, 0, 0);
        acc[0][2] = __builtin_amdgcn_mfma_f32_16x16x32_bf16(a00, bfr2, acc[0][2], 0, 0, 0);
        acc[0][3] = __builtin_amdgcn_mfma_f32_16x16x32_bf16(a00, bfr3, acc[0][3], 0, 0, 0);
        acc[1][0] = __builtin_amdgcn_mfma_f32_16x16x32_bf16(a10, bfr0, acc[1][0], 0, 0, 0);
        acc[1][1] = __builtin_amdgcn_mfma_f32_16x16x32_bf16(a10, bfr1, acc[1][1], 0, 0, 0);
        acc[1][2] = __builtin_amdgcn_mfma_f32_16x16x32_bf16(a10, bfr2, acc[1][2], 0, 0, 0);
        acc[1][3] = __builtin_amdgcn_mfma_f32_16x16x32_bf16(a10, bfr3, acc[1][3], 0, 0, 0);
        acc[0][0] = __builtin_amdgcn_mfma_f32_16x16x32_bf16(a01, bfs0, acc[0][0], 0, 0, 0);
        acc[0][1] = __builtin_amdgcn_mfma_f32_16x16x32_bf16(a01, bfs1, acc[0][1], 0, 0, 0);
        acc[0][2] = __builtin_amdgcn_mfma_f32_16x16x32_bf16(a01, bfs2, acc[0][2], 0, 0, 0);
        acc[0][3] = __builtin_amdgcn_mfma_f32_16x16x32_bf16(a01, bfs3, acc[0][3], 0, 0, 0);
        acc[1][0] = __builtin_amdgcn_mfma_f32_16x16x32_bf16(a11, bfs0, acc[1][0], 0, 0, 0);
        acc[1][1] = __builtin_amdgcn_mfma_f32_16x16x32_bf16(a11, bfs1, acc[1][1], 0, 0, 0);
        acc[1][2] = __builtin_amdgcn_mfma_f32_16x16x32_bf16(a11, bfs2, acc[1][2], 0, 0, 0);
        acc[1][3] = __builtin_amdgcn_mfma_f32_16x16x32_bf16(a11, bfs3, acc[1][3], 0, 0, 0);
        __builtin_amdgcn_s_setprio(0);
        SBAR();
        // ---------- phase 1: A m-half 1 (B frags reused from registers) ----------
        if (t + 2 < NTILE) stage_ph1(t + 2);
        bf16x8 a20, a21, a30, a31;
        a20 = *reinterpret_cast<const bf16x8*>(sb_ + a_rb + 2 * 2048 + sw0);
        a21 = *reinterpret_cast<const bf16x8*>(sb_ + a_rb + 2 * 2048 + sw1);
        a30 = *reinterpret_cast<const bf16x8*>(sb_ + a_rb + 3 * 2048 + sw0);
        a31 = *reinterpret_cast<const bf16x8*>(sb_ + a_rb + 3 * 2048 + sw1);
        SBAR();
        asm volatile("s_waitcnt lgkmcnt(0)" ::: "memory");
        __builtin_amdgcn_sched_barrier(0);
        __builtin_amdgcn_s_setprio(1);
        acc[2][0] = __builtin_amdgcn_mfma_f32_16x16x32_bf16(a20, bfr0, acc[2][0], 0, 0, 0);
        acc[2][1] = __builtin_amdgcn_mfma_f32_16x16x32_bf16(a20, bfr1, acc[2][1], 0, 0, 0);
        acc[2][2] = __builtin_amdgcn_mfma_f32_16x16x32_bf16(a20, bfr2, acc[2][2], 0, 0, 0);
        acc[2][3] = __builtin_amdgcn_mfma_f32_16x16x32_bf16(a20, bfr3, acc[2][3], 0, 0, 0);
        acc[3][0] = __builtin_amdgcn_mfma_f32_16x16x32_bf16(a30, bfr0, acc[3][0], 0, 0, 0);
        acc[3][1] = __builtin_amdgcn_mfma_f32_16x16x32_bf16(a30, bfr1, acc[3][1], 0, 0, 0);
        acc[3][2] = __builtin_amdgcn_mfma_f32_16x16x32_bf16(a30, bfr2, acc[3][2], 0, 0, 0);
        acc[3][3] = __builtin_amdgcn_mfma_f32_16x16x32_bf16(a30, bfr3, acc[3][3], 0, 0, 0);
        acc[2][0] = __builtin_amdgcn_mfma_f32_16x16x32_bf16(a21, bfs0, acc[2][0], 0, 0, 0);
        acc[2][1] = __builtin_amdgcn_mfma_f32_16x16x32_bf16(a21, bfs1, acc[2][1], 0, 0, 0);
        acc[2][2] = __builtin_amdgcn_mfma_f32_16x16x32_bf16(a21, bfs2, acc[2][2], 0, 0, 0);
        acc[2][3] = __builtin_amdgcn_mfma_f32_16x16x32_bf16(a21, bfs3, acc[2][3], 0, 0, 0);
        acc[3][0] = __builtin_amdgcn_mfma_f32_16x16x32_bf16(a31, bfs0, acc[3][0], 0, 0, 0);
        acc[3][1] = __builtin_amdgcn_mfma_f32_16x16x32_bf16(a31, bfs1, acc[3][1], 0, 0, 0);
        acc[3][2] = __builtin_amdgcn_mfma_f32_16x16x32_bf16(a31, bfs2, acc[3][2], 0, 0, 0);
        acc[3][3] = __builtin_amdgcn_mfma_f32_16x16x32_bf16(a31, bfs3, acc[3][3], 0, 0, 0);
        __builtin_amdgcn_s_setprio(0);
        if (t < NTILE - 2)       VMWAIT(6);   // tile t+1 landed; t+2's 6 stay in flight
        else if (t == NTILE - 2) VMWAIT(0);   // tail: tile NTILE-1 landed
        SBAR();
    }

    // ---- epilogue: per-wave LDS transpose -> 16 B/lane coalesced stores ----
    // [64][72] bf16 per wave (9216 B, 8 waves = 73728 <= smem); rows 2-way max both phases
    float bv[4];
    {
        int nb = e * BROWS + n0 + wn * 64 + lm;
#pragma unroll
        for (int fn = 0; fn < 4; ++fn) bv[fn] = bias[nb + fn * 16];
    }
    __bf16* ep = (__bf16*)(smem) + w * (64 * 72);
#pragma unroll
    for (int fn = 0; fn < 4; ++fn) {
#pragma unroll
        for (int fm = 0; fm < 4; ++fm)
#pragma unroll
            for (int i = 0; i < 4; ++i) {
                float v = acc[fm][fn][i] + bv[fn];
                if (!PASS2) v = v / (1.f + __expf(-v));
                ep[(fm * 16 + q * 4 + i) * 72 + fn * 16 + lm] = (__bf16)v;
            }
    }
    __syncthreads();
    int rr = lane >> 3, ccol = (lane & 7) * 8;
#pragma unroll
    for (int rep = 0; rep < 8; ++rep) {
        int rw = rep * 8 + rr;
        int slot = m0 + wm * 64 + rw;
        bf16x8 vv = *reinterpret_cast<const bf16x8*>(&ep[rw * 72 + ccol]);
        if (slot < cnt)
            *reinterpret_cast<bf16x8*>(
                &Out_base[((size_t)e * CAP + slot) * BROWS + n0 + wn * 64 + ccol]) = vv;
    }
}

// ---------------- combine: out[t] = w0*y[idx0] + w1*y[idx1]; block 0 thread 0 does aux ----------------
__global__ __launch_bounds__(256) void combine_kernel(const __bf16* __restrict__ ybuf,
                                                      const int2* __restrict__ tinfo_idx,
                                                      const float2* __restrict__ tinfo_w,
                                                      const int* __restrict__ counts,
                                                      const float* __restrict__ psum,
                                                      float* __restrict__ out) {
    int tid = threadIdx.x;
    if (blockIdx.x == 0 && tid == 0) {
        float s = 0.f;
#pragma unroll
        for (int e = 0; e < 8; ++e)
            s += ((float)counts[e] / (float)(N_TOK * 2)) * (psum[e] / (float)N_TOK);
        out[(size_t)N_TOK * D_MODEL] = 8.f * s;
    }
    int t = blockIdx.x * 2 + (tid >> 7);
    int d0 = (tid & 127) * 8;
    int2 ix = tinfo_idx[t];
    float2 w = tinfo_w[t];
    bf16x8 ya = *reinterpret_cast<const bf16x8*>(ybuf + (size_t)ix.x * D_MODEL + d0);
    bf16x8 yb = *reinterpret_cast<const bf16x8*>(ybuf + (size_t)ix.y * D_MODEL + d0);
    float4 o0, o1;
    o0.x = w.x * (float)ya[0] + w.y * (float)yb[0];
    o0.y = w.x * (float)ya[1] + w.y * (float)yb[1];
    o0.z = w.x * (float)ya[2] + w.y * (float)yb[2];
    o0.w = w.x * (float)ya[3] + w.y * (float)yb[3];
    o1.x = w.x * (float)ya[4] + w.y * (float)yb[4];
    o1.y = w.x * (float)ya[5] + w.y * (float)yb[5];
    o1.z = w.x * (float)ya[6] + w.y * (float)yb[6];
    o1.w = w.x * (float)ya[7] + w.y * (float)yb[7];
    float* op = out + (size_t)t * D_MODEL + d0;
    *reinterpret_cast<float4*>(op) = o0;
    *reinterpret_cast<float4*>(op + 4) = o1;
}

extern "C" void kernel_launch(void* const* d_in, const int* in_sizes, int n_in,
                              void* d_out, int out_size, void* d_ws, size_t ws_size,
                              hipStream_t stream) {
    const float* x  = (const float*)d_in[0];
    const float* rw = (const float*)d_in[1];
    const float* w1 = (const float*)d_in[2];
    const float* b1 = (const float*)d_in[3];
    const float* w2 = (const float*)d_in[4];
    const float* b2 = (const float*)d_in[5];
    float* out = (float*)d_out;

    char* ws = (char*)d_ws;
    __bf16* xb     = (__bf16*)(ws + XB_OFF);
    __bf16* w1b    = (__bf16*)(ws + W1B_OFF);
    __bf16* w2b    = (__bf16*)(ws + W2B_OFF);
    __bf16* hbuf   = (__bf16*)(ws + HBUF_OFF);
    __bf16* ybuf   = (__bf16*)(ws + YBUF_OFF);
    int*    counts = (int*)(ws + CNT_OFF);
    float*  psum   = (float*)(ws + PSUM_OFF);
    int*    tok    = (int*)(ws + TOK_OFF);
    int2*   tix    = (int2*)(ws + TIX_OFF);
    float2* tiw    = (float2*)(ws + TIW_OFF);

    hipMemsetAsync(ws + CNT_OFF, 0, 64, stream);   // counts + psum

    // prep: router (64) + x cvt (2048) + w1 cvt (8192)
    prep_kernel<<<64 + 2048 + 8192, 256, 0, stream>>>(x, rw, w1, xb, w1b,
                                                      counts, psum, tok, tix, tiw);

    // pass1: 1024 GEMM blocks (BM=256,BN=128) interleaved 1:4 with 4096 w2-cvt blocks
    constexpr int NG1 = 8 * (FFN_H / 128) * (CAP / 256);
    ffn_kernel<D_MODEL, false, true><<<NG1 * 5, 512, 0, stream>>>(
        xb, w1b, b1, counts, tok, hbuf, w2, w2b);

    constexpr int NG2 = 8 * (D_MODEL / 128) * (CAP / 256);
    ffn_kernel<FFN_H, true, false><<<NG2, 512, 0, stream>>>(
        hbuf, w2b, b2, counts, tok, ybuf, nullptr, nullptr);

    combine_kernel<<<N_TOK / 2, 256, 0, stream>>>(ybuf, tix, tiw, counts, psum, out);
}

// Round 7
// 290.676 us; speedup vs baseline: 1.0808x; 1.0808x over previous
//
#include <hip/hip_runtime.h>
#include <cstdint>
#include <cstddef>

#define D_MODEL 1024
#define N_EXPERTS 8
#define FFN_H 2048
#define N_TOK 4096
#define CAP 2048

typedef float f32x4 __attribute__((ext_vector_type(4)));
typedef __bf16 bf16x8 __attribute__((ext_vector_type(8)));

// ---- workspace layout (bytes) ----
static constexpr size_t XB_OFF   = 0;                                                  // [N][D] bf16
static constexpr size_t W1B_OFF  = XB_OFF  + (size_t)N_TOK * D_MODEL * 2;
static constexpr size_t W2B_OFF  = W1B_OFF + (size_t)N_EXPERTS * FFN_H * D_MODEL * 2;
static constexpr size_t HBUF_OFF = W2B_OFF + (size_t)N_EXPERTS * D_MODEL * FFN_H * 2;  // [E][CAP][H] bf16
static constexpr size_t YBUF_OFF = HBUF_OFF + (size_t)N_EXPERTS * CAP * FFN_H * 2;     // [E][CAP][D] bf16
static constexpr size_t CNT_OFF  = YBUF_OFF + (size_t)N_EXPERTS * CAP * D_MODEL * 2;   // [8] int
static constexpr size_t PSUM_OFF = CNT_OFF + 32;                                       // [8] float
static constexpr size_t TOK_OFF  = PSUM_OFF + 32;                                      // [E][CAP] int
static constexpr size_t TIX_OFF  = TOK_OFF + (size_t)N_EXPERTS * CAP * 4;              // [N] int2
static constexpr size_t TIW_OFF  = TIX_OFF + (size_t)N_TOK * 8;                        // [N] float2

// async global->LDS, 16 B per lane; LDS dest = wave-uniform base + lane*16
__device__ __forceinline__ void async_ld16(const void* g, void* l) {
    __builtin_amdgcn_global_load_lds(
        (const __attribute__((address_space(1))) unsigned int*)g,
        (__attribute__((address_space(3))) unsigned int*)l, 16, 0, 0);
}

__device__ __forceinline__ void cvt_block256(const float* __restrict__ src,
                                             __bf16* __restrict__ dst,
                                             int c, int tid) {
    size_t i = (size_t)c * 2048 + (size_t)tid * 8;
    float4 a = *reinterpret_cast<const float4*>(src + i);
    float4 d = *reinterpret_cast<const float4*>(src + i + 4);
    bf16x8 r;
    r[0] = (__bf16)a.x; r[1] = (__bf16)a.y; r[2] = (__bf16)a.z; r[3] = (__bf16)a.w;
    r[4] = (__bf16)d.x; r[5] = (__bf16)d.y; r[6] = (__bf16)d.z; r[7] = (__bf16)d.w;
    *reinterpret_cast<bf16x8*>(dst + i) = r;
}

// ---------------- prep: blocks 0..63 = router; 64..2111 = x cvt; 2112.. = w1 cvt ----------------
__global__ __launch_bounds__(256) void prep_kernel(const float* __restrict__ x,
                                                   const float* __restrict__ rw,
                                                   const float* __restrict__ w1,
                                                   __bf16* __restrict__ xb,
                                                   __bf16* __restrict__ w1b,
                                                   int* __restrict__ counts,
                                                   float* __restrict__ psum,
                                                   int* __restrict__ tok_list,
                                                   int2* __restrict__ tinfo_idx,
                                                   float2* __restrict__ tinfo_w) {
    __shared__ float rws[N_EXPERTS * D_MODEL];   // 32 KB (router blocks only)
    __shared__ int s_e0[64], s_e1[64], s_r0[64], s_r1[64];
    __shared__ float s_w0[64], s_w1[64];
    __shared__ int hist[8], base[8];
    __shared__ float pacc[8];

    int tid = threadIdx.x;
    int b = blockIdx.x;
    if (b >= 64) {
        int c = b - 64;
        if (c < 2048) cvt_block256(x, xb, c, tid);
        else          cvt_block256(w1, w1b, c - 2048, tid);
        return;
    }

    // ---- router path: 64 tokens per block ----
    for (int i = tid * 4; i < N_EXPERTS * D_MODEL; i += 256 * 4)
        *reinterpret_cast<float4*>(&rws[i]) = *reinterpret_cast<const float4*>(&rw[i]);
    if (tid < 8) { hist[tid] = 0; pacc[tid] = 0.f; }
    __syncthreads();

    int wave = tid >> 6, lane = tid & 63;
    float psacc[8] = {};
    for (int it = 0; it < 16; ++it) {
        int li = wave * 16 + it;
        int t = b * 64 + li;
        const float* xr = x + (size_t)t * D_MODEL;
        float acc[8] = {};
#pragma unroll
        for (int i = 0; i < D_MODEL / 64; ++i) {
            float xv = xr[lane + 64 * i];
#pragma unroll
            for (int e = 0; e < 8; ++e) acc[e] += xv * rws[e * D_MODEL + lane + 64 * i];
        }
        float logit[8];
#pragma unroll
        for (int e = 0; e < 8; ++e) {
            float v = acc[e];
            for (int off = 32; off; off >>= 1) v += __shfl_xor(v, off);
            logit[e] = v;
        }
        float mx = logit[0];
#pragma unroll
        for (int e = 1; e < 8; ++e) mx = fmaxf(mx, logit[e]);
        float p[8], s = 0.f;
#pragma unroll
        for (int e = 0; e < 8; ++e) { p[e] = expf(logit[e] - mx); s += p[e]; }
        float inv = 1.f / s;
#pragma unroll
        for (int e = 0; e < 8; ++e) { p[e] *= inv; psacc[e] += p[e]; }
        int e0 = 0; float p0 = p[0];
#pragma unroll
        for (int e = 1; e < 8; ++e) if (p[e] > p0) { p0 = p[e]; e0 = e; }
        int e1 = -1; float p1 = -1.f;
#pragma unroll
        for (int e = 0; e < 8; ++e) if (e != e0 && p[e] > p1) { p1 = p[e]; e1 = e; }
        float invw = 1.f / (p0 + p1);
        if (lane == 0) {
            s_e0[li] = e0; s_e1[li] = e1;
            s_w0[li] = p0 * invw; s_w1[li] = p1 * invw;
        }
    }
    if (lane == 0)
#pragma unroll
        for (int e = 0; e < 8; ++e) atomicAdd(&pacc[e], psacc[e]);
    __syncthreads();

    if (tid < 64) {
        s_r0[tid] = atomicAdd(&hist[s_e0[tid]], 1);
        s_r1[tid] = atomicAdd(&hist[s_e1[tid]], 1);
    }
    __syncthreads();
    if (tid < 8) {
        base[tid] = atomicAdd(&counts[tid], hist[tid]);   // device-scope, 512 total
        atomicAdd(&psum[tid], pacc[tid]);
    }
    __syncthreads();
    if (tid < 64) {
        int t = b * 64 + tid;
        int e0 = s_e0[tid], e1 = s_e1[tid];
        int q0 = min(base[e0] + s_r0[tid], CAP - 1);
        int q1 = min(base[e1] + s_r1[tid], CAP - 1);
        tok_list[e0 * CAP + q0] = t;
        tok_list[e1 * CAP + q1] = t;
        tinfo_idx[t] = make_int2(e0 * CAP + q0, e1 * CAP + q1);
        tinfo_w[t] = make_float2(s_w0[tid], s_w1[tid]);
    }
}

// ---------------- grouped GEMM, 128x128 tile, BK=32, 2-deep double-buffer (36,864 B LDS
//                  -> 4 blocks/CU), global_load_lds, both-sides bank swizzle,
//                  LDS-transpose vectorized epilogue ----------------
// CVT instantiation (pass1): each GEMM block converts its 8192-float chunk of w2 as a
// PROLOGUE (8 float4 loads -> cvt -> 4 bf16x8 stores) before the K-loop. No separate cvt
// blocks -> no CU-slot churn / LDS-reservation conflict (R5/R6 lessons). Stores are
// fire-and-forget; first __syncthreads drains them; w2b is only read by the next kernel.
// Runs BEFORE the m0>=cnt early-exit so w2 coverage is complete regardless of routing.
// LDS map (36864 B): A bufs at 0/8192; B bufs at 16384/24576 ([128][32] bf16 chunks,
// col-block cb stored at cb ^ ((row>>1)&3)); epilogue overlay per-wave [64][72] at wv*9216.
template <int KDIM, bool PASS2, bool CVT>
__global__ __launch_bounds__(256, 4) void ffn_kernel(const __bf16* __restrict__ A_base,
                                                     const __bf16* __restrict__ B_base,
                                                     const float* __restrict__ bias,
                                                     const int* __restrict__ counts,
                                                     const int* __restrict__ tok_list,
                                                     __bf16* __restrict__ Out_base,
                                                     const float* __restrict__ cvt_src,
                                                     __bf16* __restrict__ cvt_dst) {
    constexpr int BROWS = PASS2 ? D_MODEL : FFN_H;
    constexpr int NT = BROWS / 128;
    constexpr int NSTEP = KDIM / 32;
    int gid = blockIdx.x;
    int tid = threadIdx.x;

    if (CVT) {
        // prologue w2 conversion: 8192 floats per block, 32 per thread
        size_t i = (size_t)gid * 8192 + (size_t)tid * 32;
#pragma unroll
        for (int jj = 0; jj < 2; ++jj) {
            float4 a = *reinterpret_cast<const float4*>(cvt_src + i + jj * 16);
            float4 b4 = *reinterpret_cast<const float4*>(cvt_src + i + jj * 16 + 4);
            float4 c4 = *reinterpret_cast<const float4*>(cvt_src + i + jj * 16 + 8);
            float4 d = *reinterpret_cast<const float4*>(cvt_src + i + jj * 16 + 12);
            bf16x8 r0, r1;
            r0[0] = (__bf16)a.x; r0[1] = (__bf16)a.y; r0[2] = (__bf16)a.z; r0[3] = (__bf16)a.w;
            r0[4] = (__bf16)b4.x; r0[5] = (__bf16)b4.y; r0[6] = (__bf16)b4.z; r0[7] = (__bf16)b4.w;
            r1[0] = (__bf16)c4.x; r1[1] = (__bf16)c4.y; r1[2] = (__bf16)c4.z; r1[3] = (__bf16)c4.w;
            r1[4] = (__bf16)d.x; r1[5] = (__bf16)d.y; r1[6] = (__bf16)d.z; r1[7] = (__bf16)d.w;
            *reinterpret_cast<bf16x8*>(cvt_dst + i + jj * 16) = r0;
            *reinterpret_cast<bf16x8*>(cvt_dst + i + jj * 16 + 8) = r1;
        }
    }

    int e = gid & 7;                 // expert fastest -> XCD-pinned weights
    int r = gid >> 3;
    int n0 = (r % NT) * 128;
    int m0 = (r / NT) * 128;
    int cnt = min(counts[e], CAP);
    if (m0 >= cnt) return;

    __shared__ char smem[36864];

    int* s_tok = (int*)smem;
    if (!PASS2 && tid < 128) {
        int slot = min(m0 + tid, cnt - 1);
        s_tok[tid] = tok_list[e * CAP + slot];
    }
    __syncthreads();

    // staging source pre-swizzle: 16-B col block XOR'd with ((row>>1)&3); LDS dest linear
    int colk = ((tid & 3) ^ ((tid >> 3) & 3)) * 8;
    const __bf16 *a_src0, *a_src1;
    if (PASS2) {
        int s0 = min(m0 + (tid >> 2), cnt - 1);
        int s1 = min(m0 + 64 + (tid >> 2), cnt - 1);
        a_src0 = A_base + ((size_t)e * CAP + s0) * KDIM + colk;
        a_src1 = A_base + ((size_t)e * CAP + s1) * KDIM + colk;
    } else {
        a_src0 = A_base + (size_t)s_tok[tid >> 2] * KDIM + colk;
        a_src1 = A_base + (size_t)s_tok[64 + (tid >> 2)] * KDIM + colk;
    }
    const __bf16* b_src0 = B_base + ((size_t)e * BROWS + n0 + (tid >> 2)) * KDIM + colk;
    const __bf16* b_src1 = b_src0 + (size_t)64 * KDIM;
    __syncthreads();   // s_tok consumed; smem reusable for staging

    int wv = tid >> 6, lane = tid & 63;
    int wm = wv >> 1, wn = wv & 1;
    int lm = lane & 15, q = lane >> 4;
    // read-side swizzle matches the source pre-swizzle (same involution)
    int rsw = (q ^ ((lm >> 1) & 3)) * 8;
    int a_base = (wm * 64 + lm) * 32 + rsw;
    int b_base = (wn * 64 + lm) * 32 + rsw;
    int wofs = wv * 1024;

    f32x4 acc[4][4] = {};

    auto stage = [&](int t) {
        int k0 = t * 32;
        int bo = (t & 1) * 8192;
        char* la = smem + bo + wofs;
        char* lb = smem + 16384 + bo + wofs;
        async_ld16(a_src0 + k0, la);
        async_ld16(a_src1 + k0, la + 4096);
        async_ld16(b_src0 + k0, lb);
        async_ld16(b_src1 + k0, lb + 4096);
    };
    auto compute = [&](int t) {
        int bo = (t & 1) * 8192;
        const __bf16* pa = (const __bf16*)(smem + bo);
        const __bf16* pb = (const __bf16*)(smem + 16384 + bo);
        bf16x8 af[4], bfg[4];
#pragma unroll
        for (int f = 0; f < 4; ++f) {
            af[f]  = *reinterpret_cast<const bf16x8*>(&pa[a_base + f * 512]);
            bfg[f] = *reinterpret_cast<const bf16x8*>(&pb[b_base + f * 512]);
        }
#pragma unroll
        for (int fm = 0; fm < 4; ++fm)
#pragma unroll
            for (int fn = 0; fn < 4; ++fn)
                acc[fm][fn] = __builtin_amdgcn_mfma_f32_16x16x32_bf16(af[fm], bfg[fn], acc[fm][fn], 0, 0, 0);
    };

    stage(0);
    __syncthreads();
    for (int t = 0; t < NSTEP; ++t) {
        if (t + 1 < NSTEP) stage(t + 1);   // fire-and-forget into other buffer
        compute(t);
        __syncthreads();   // drains vmcnt+lgkmcnt: next tile landed, buf t fully read
    }

    // ---- epilogue: per-wave LDS transpose -> 16 B/lane coalesced stores ----
    // [64][72] bf16 per wave: row stride 144 B (16-B aligned, 2-way max both phases)
    __bf16* ep = (__bf16*)(smem) + wv * (64 * 72);
#pragma unroll
    for (int fn = 0; fn < 4; ++fn) {
        int n = n0 + wn * 64 + fn * 16 + lm;
        float bv = bias[e * BROWS + n];
#pragma unroll
        for (int fm = 0; fm < 4; ++fm)
#pragma unroll
            for (int i = 0; i < 4; ++i) {
                float v = acc[fm][fn][i] + bv;
                if (!PASS2) v = v / (1.f + __expf(-v));
                ep[(fm * 16 + q * 4 + i) * 72 + fn * 16 + lm] = (__bf16)v;
            }
    }
    __syncthreads();
    int rr = lane >> 3, ccol = (lane & 7) * 8;
#pragma unroll
    for (int rep = 0; rep < 8; ++rep) {
        int rw = rep * 8 + rr;
        int slot = m0 + wm * 64 + rw;
        bf16x8 vv = *reinterpret_cast<const bf16x8*>(&ep[rw * 72 + ccol]);
        if (slot < cnt)
            *reinterpret_cast<bf16x8*>(
                &Out_base[((size_t)e * CAP + slot) * BROWS + n0 + wn * 64 + ccol]) = vv;
    }
}

// ---------------- combine: out[t] = w0*y[idx0] + w1*y[idx1]; block 0 thread 0 does aux ----------------
__global__ __launch_bounds__(256) void combine_kernel(const __bf16* __restrict__ ybuf,
                                                      const int2* __restrict__ tinfo_idx,
                                                      const float2* __restrict__ tinfo_w,
                                                      const int* __restrict__ counts,
                                                      const float* __restrict__ psum,
                                                      float* __restrict__ out) {
    int tid = threadIdx.x;
    if (blockIdx.x == 0 && tid == 0) {
        float s = 0.f;
#pragma unroll
        for (int e = 0; e < 8; ++e)
            s += ((float)counts[e] / (float)(N_TOK * 2)) * (psum[e] / (float)N_TOK);
        out[(size_t)N_TOK * D_MODEL] = 8.f * s;
    }
    int t = blockIdx.x * 2 + (tid >> 7);
    int d0 = (tid & 127) * 8;
    int2 ix = tinfo_idx[t];
    float2 w = tinfo_w[t];
    bf16x8 ya = *reinterpret_cast<const bf16x8*>(ybuf + (size_t)ix.x * D_MODEL + d0);
    bf16x8 yb = *reinterpret_cast<const bf16x8*>(ybuf + (size_t)ix.y * D_MODEL + d0);
    float4 o0, o1;
    o0.x = w.x * (float)ya[0] + w.y * (float)yb[0];
    o0.y = w.x * (float)ya[1] + w.y * (float)yb[1];
    o0.z = w.x * (float)ya[2] + w.y * (float)yb[2];
    o0.w = w.x * (float)ya[3] + w.y * (float)yb[3];
    o1.x = w.x * (float)ya[4] + w.y * (float)yb[4];
    o1.y = w.x * (float)ya[5] + w.y * (float)yb[5];
    o1.z = w.x * (float)ya[6] + w.y * (float)yb[6];
    o1.w = w.x * (float)ya[7] + w.y * (float)yb[7];
    float* op = out + (size_t)t * D_MODEL + d0;
    *reinterpret_cast<float4*>(op) = o0;
    *reinterpret_cast<float4*>(op + 4) = o1;
}

extern "C" void kernel_launch(void* const* d_in, const int* in_sizes, int n_in,
                              void* d_out, int out_size, void* d_ws, size_t ws_size,
                              hipStream_t stream) {
    const float* x  = (const float*)d_in[0];
    const float* rw = (const float*)d_in[1];
    const float* w1 = (const float*)d_in[2];
    const float* b1 = (const float*)d_in[3];
    const float* w2 = (const float*)d_in[4];
    const float* b2 = (const float*)d_in[5];
    float* out = (float*)d_out;

    char* ws = (char*)d_ws;
    __bf16* xb     = (__bf16*)(ws + XB_OFF);
    __bf16* w1b    = (__bf16*)(ws + W1B_OFF);
    __bf16* w2b    = (__bf16*)(ws + W2B_OFF);
    __bf16* hbuf   = (__bf16*)(ws + HBUF_OFF);
    __bf16* ybuf   = (__bf16*)(ws + YBUF_OFF);
    int*    counts = (int*)(ws + CNT_OFF);
    float*  psum   = (float*)(ws + PSUM_OFF);
    int*    tok    = (int*)(ws + TOK_OFF);
    int2*   tix    = (int2*)(ws + TIX_OFF);
    float2* tiw    = (float2*)(ws + TIW_OFF);

    hipMemsetAsync(ws + CNT_OFF, 0, 64, stream);   // counts + psum

    // prep: router (64) + x cvt (2048) + w1 cvt (8192)
    prep_kernel<<<64 + 2048 + 8192, 256, 0, stream>>>(x, rw, w1, xb, w1b,
                                                      counts, psum, tok, tix, tiw);

    // pass1: 2048 GEMM blocks; each converts its 8192-float chunk of w2 in its prologue
    constexpr int NG1 = 8 * (FFN_H / 128) * (CAP / 128);
    static_assert((size_t)NG1 * 8192 == (size_t)N_EXPERTS * D_MODEL * FFN_H, "w2 coverage");
    ffn_kernel<D_MODEL, false, true><<<NG1, 256, 0, stream>>>(
        xb, w1b, b1, counts, tok, hbuf, w2, w2b);

    constexpr int NG2 = 8 * (D_MODEL / 128) * (CAP / 128);
    ffn_kernel<FFN_H, true, false><<<NG2, 256, 0, stream>>>(
        hbuf, w2b, b2, counts, tok, ybuf, nullptr, nullptr);

    combine_kernel<<<N_TOK / 2, 256, 0, stream>>>(ybuf, tix, tiw, counts, psum, out);
}